// Round 9
// baseline (21971.397 us; speedup 1.0000x reference)
//
#include <hip/hip_runtime.h>
#include <cstdint>
#include <cstddef>

// Problem constants (fixed by the reference)
#define DD 1024
#define TT 2048
#define NL 4
// Recurrence: 256 blocks x 512 threads (8 waves), 1 block/CU.
#define NBLK 256
#define NTHR 512
// x-part GEMM tiles
#define GT 128
#define GC 128
#define GK 16

__device__ __forceinline__ float fast_tanh(float x) {
  float e = __expf(2.f * x);
  return 1.f - 2.f / (e + 1.f);
}

// Two 16B agent-scope loads (consecutive 32B), one waitcnt -> one round-trip.
__device__ __forceinline__ void agent_load32(const float* p, float4& a,
                                             float4& b) {
  asm volatile("global_load_dwordx4 %0, %2, off sc1\n\t"
               "global_load_dwordx4 %1, %2, off offset:16 sc1\n\t"
               "s_waitcnt vmcnt(0)"
               : "=&v"(a), "=&v"(b) : "v"(p) : "memory");
}
// 16B agent-scope store as two 8B atomic stores (off critical path).
__device__ __forceinline__ void agent_store16(float* p, float4 v) {
  unsigned long long lo =
      ((unsigned long long)__float_as_uint(v.y) << 32) | __float_as_uint(v.x);
  unsigned long long hi =
      ((unsigned long long)__float_as_uint(v.w) << 32) | __float_as_uint(v.z);
  __hip_atomic_store((unsigned long long*)p, lo,
                     __ATOMIC_RELAXED, __HIP_MEMORY_SCOPE_AGENT);
  __hip_atomic_store(((unsigned long long*)p) + 1, hi,
                     __ATOMIC_RELAXED, __HIP_MEMORY_SCOPE_AGENT);
}

__global__ __launch_bounds__(1024) void prep_kernel(
    const float* __restrict__ sp, const float* __restrict__ rn_p,
    const float* __restrict__ w, const float* __restrict__ b,
    float* __restrict__ X0) {
  int i = blockIdx.x * blockDim.x + threadIdx.x;   // over T*D
  float rn = rn_p[0];
  int c = i & (DD - 1);
  X0[i] = sp[i] + rn * w[c] + b[c];
}

// ZX[t][piece*1024 + c] = sum_k X[t][k] * W[piece][k][c] + b[piece][c]
__global__ __launch_bounds__(256) void xgemm_kernel(
    const float* __restrict__ X,    // [TT, DD]
    const float* __restrict__ Wf1, const float* __restrict__ Wf2,
    const float* __restrict__ Wta, const float* __restrict__ Wtb,
    const float* __restrict__ bf1, const float* __restrict__ bf2,
    const float* __restrict__ bta, const float* __restrict__ btb,
    float* __restrict__ ZX, int layer)
{
  __shared__ float As[GK][GT + 4];
  __shared__ float Bs[GK][GC + 4];

  const int tid = threadIdx.x;
  const int ct = blockIdx.x;                 // col tile 0..31
  const int rt = blockIdx.y;                 // row tile 0..15
  const int c0 = ct * GC;
  const int B  = c0 >> 10;
  const int cc0 = c0 & (DD - 1);
  const float* Wsel = (B == 0) ? Wf1 : (B == 1) ? Wf2 : (B == 2) ? Wta : Wtb;
  const float* bsel = (B == 0) ? bf1 : (B == 1) ? bf2 : (B == 2) ? bta : btb;
  const float* Wb = Wsel + (size_t)layer * 2 * DD * DD;   // x rows 0..1023
  const float* bb = bsel + (size_t)layer * DD + cc0;

  const int ty = tid >> 4, tx = tid & 15;

  float acc[8][8];
#pragma unroll
  for (int i = 0; i < 8; ++i)
#pragma unroll
    for (int j = 0; j < 8; ++j) acc[i][j] = 0.f;

  for (int k0 = 0; k0 < DD; k0 += GK) {
#pragma unroll
    for (int j = 0; j < 2; ++j) {
      int idx = j * 256 + tid;
      int r = idx >> 2;
      int kq = (idx & 3) * 4;
      float4 v = *(const float4*)&X[(size_t)(rt * GT + r) * DD + k0 + kq];
      As[kq + 0][r] = v.x; As[kq + 1][r] = v.y;
      As[kq + 2][r] = v.z; As[kq + 3][r] = v.w;
    }
#pragma unroll
    for (int j = 0; j < 2; ++j) {
      int idx = j * 256 + tid;
      int kk = idx >> 5;
      int cq = (idx & 31) * 4;
      *(float4*)&Bs[kk][cq] =
          *(const float4*)&Wb[(size_t)(k0 + kk) * DD + cc0 + cq];
    }
    __syncthreads();
#pragma unroll
    for (int k = 0; k < GK; ++k) {
      float a[8], bv[8];
      *(float4*)&a[0]  = *(const float4*)&As[k][ty * 8];
      *(float4*)&a[4]  = *(const float4*)&As[k][ty * 8 + 4];
      *(float4*)&bv[0] = *(const float4*)&Bs[k][tx * 8];
      *(float4*)&bv[4] = *(const float4*)&Bs[k][tx * 8 + 4];
#pragma unroll
      for (int i = 0; i < 8; ++i)
#pragma unroll
        for (int j = 0; j < 8; ++j) acc[i][j] = fmaf(a[i], bv[j], acc[i][j]);
    }
    __syncthreads();
  }

  float bias[8];
#pragma unroll
  for (int j = 0; j < 8; ++j) bias[j] = bb[tx * 8 + j];
#pragma unroll
  for (int i = 0; i < 8; ++i) {
    int t = rt * GT + ty * 8 + i;
    float4 o0 = make_float4(acc[i][0] + bias[0], acc[i][1] + bias[1],
                            acc[i][2] + bias[2], acc[i][3] + bias[3]);
    float4 o1 = make_float4(acc[i][4] + bias[4], acc[i][5] + bias[5],
                            acc[i][6] + bias[6], acc[i][7] + bias[7]);
    *(float4*)&ZX[(size_t)t * 4096 + c0 + tx * 8]     = o0;
    *(float4*)&ZX[(size_t)t * 4096 + c0 + tx * 8 + 4] = o1;
  }
}

// h-part recurrence with stamped full-line h-exchange.
// HX[t][bid] is a private 64B line of 8B pairs (h_value, stamp), stamp =
// layer*TT + t (unique per slot, never equals 0xAA poison or another
// layer's leftover). Producer wave writes the full line (8 lanes x 8B =
// no partial-line HBM RMW); readers issue 2x16B sc1 loads, accept when
// all 4 embedded stamps match. No memset / NaN prefill needed.
__global__ __launch_bounds__(NTHR) void recur_kernel(
    const float* __restrict__ ZX,   // [TT, 4096], x-part incl. bias
    float* __restrict__ Hout,       // [TT, DD] compact (not polled)
    float* __restrict__ HX,         // [TT][256][16] floats
    const float* __restrict__ Wf1, const float* __restrict__ Wf2,
    const float* __restrict__ Wta, const float* __restrict__ Wtb,
    const float* __restrict__ dt_p, int layer,
    float* __restrict__ out_last)
{
  __shared__ float4 wlds[8 * 8 * 64];  // [wave][seg][lane] = 64 KB
  __shared__ float hs[DD];             // h_{t-1} broadcast (4 KB)
  __shared__ float zbuf[16];

  const int tid = threadIdx.x;
  const int w   = tid >> 6;            // wave 0..7
  const int ln  = tid & 63;
  const int bid = blockIdx.x;

  const int B    = w >> 1;
  const int p    = w & 1;
  const int col0 = bid * 4 + 2 * p;
  const float* Wsel = (B == 0) ? Wf1 : (B == 1) ? Wf2 : (B == 2) ? Wta : Wtb;
  const float* Wb = Wsel + (size_t)layer * 2 * DD * DD;
  const float dtv = dt_p[0];

  // Fill W_h into LDS: rows 1024 + s*128 + 2*ln (+1), cols col0, col0+1.
#pragma unroll
  for (int s = 0; s < 8; ++s) {
    const float* a_ = Wb + (size_t)(DD + s * 128 + 2 * ln) * DD + col0;
    float2 lo = *(const float2*)a_;
    float2 hi = *(const float2*)(a_ + DD);
    wlds[(w * 8 + s) * 64 + ln] = make_float4(lo.x, lo.y, hi.x, hi.y);
  }
  *(float2*)&hs[2 * tid] = make_float2(0.f, 0.f);   // h_{-1} = 0
  __syncthreads();

  for (int t = 0; t < TT; ++t) {
    float2 zx2 = make_float2(0.f, 0.f);
    if (ln == 0) zx2 = *(const float2*)&ZX[(size_t)t * 4096 + B * 1024 + col0];

    if (t > 0) {
      const unsigned gs = (unsigned)(layer * TT + (t - 1));  // slot stamp
      if (w == 7) {
        // Producer: gate math for h(t-1) (zbuf from prev iter) in lanes 0..3.
        float h = 0.f;
        if (ln < 4) {
          float z1 = zbuf[ln];
          float z2 = zbuf[4 + ln];
          float za = zbuf[8 + ln];
          float zb = zbuf[12 + ln];
          float f1 = fast_tanh(z1);
          float f2 = fast_tanh(z2);
          float g = 1.f / (1.f + __expf(za * dtv - zb));
          h = g * f1 + (1.f - g) * f2;
        }
        // Uniform gathers (shfl outside divergence).
        float hv0 = __shfl(h, 0, 64), hv1 = __shfl(h, 1, 64);
        float hv2 = __shfl(h, 2, 64), hv3 = __shfl(h, 3, 64);
        float he  = __shfl(h, ln & 3, 64);
        if (ln < 8) {
          // Full-line store: 8 lanes x 8B pairs (h, stamp), consecutive.
          unsigned long long pr =
              ((unsigned long long)gs << 32) | __float_as_uint(he);
          unsigned long long* line =
              (unsigned long long*)(HX + ((size_t)(t - 1) * 256 + bid) * 16);
          __hip_atomic_store(line + ln, pr,
                             __ATOMIC_RELAXED, __HIP_MEMORY_SCOPE_AGENT);
        } else if (ln == 8) {
          // Compact Hout (next layer's xgemm input) -- nobody polls this.
          agent_store16(&Hout[(size_t)(t - 1) * DD + bid * 4],
                        make_float4(hv0, hv1, hv2, hv3));
        }
      } else if (w < 4) {
        // Pollers: lane b = w*64+ln polls block b's line of step t-1.
        const int b = w * 64 + ln;
        const float* base = HX + ((size_t)(t - 1) * 256 + b) * 16;
        float4 v0, v1; int guard = 0;
        while (true) {
          agent_load32(base, v0, v1);
          bool ok = (__float_as_uint(v0.y) == gs) &&
                    (__float_as_uint(v0.w) == gs) &&
                    (__float_as_uint(v1.y) == gs) &&
                    (__float_as_uint(v1.w) == gs);
          if (__all(ok)) break;
          if (++guard > (1 << 24)) break;
        }
        *(float4*)&hs[b * 4] = make_float4(v0.x, v0.z, v1.x, v1.z);
      }
    }
    __syncthreads();   // hs(t-1) ready

    // Dot: 2 cols per wave over the 1024 h rows (weights from LDS).
    float acc0 = 0.f, acc1 = 0.f;
#define DOTS(s) do {                                        \
      float4 m = wlds[(w * 8 + (s)) * 64 + ln];             \
      float2 v_ = *(const float2*)&hs[(s) * 128 + 2 * ln];  \
      acc0 = fmaf(v_.x, m.x, acc0);                         \
      acc0 = fmaf(v_.y, m.z, acc0);                         \
      acc1 = fmaf(v_.x, m.y, acc1);                         \
      acc1 = fmaf(v_.y, m.w, acc1);                         \
    } while (0)
    DOTS(0); DOTS(1); DOTS(2); DOTS(3);
    DOTS(4); DOTS(5); DOTS(6); DOTS(7);
#undef DOTS
#pragma unroll
    for (int off = 32; off > 0; off >>= 1) {
      acc0 += __shfl_xor(acc0, off, 64);
      acc1 += __shfl_xor(acc1, off, 64);
    }
    if (ln == 0) {
      zbuf[2 * w]     = acc0 + zx2.x;   // zbuf[B*4 + 2p + q]
      zbuf[2 * w + 1] = acc1 + zx2.y;
    }
    __syncthreads();   // zbuf(t) ready
  }

  // Epilogue: h(TT-1) -> Hout (next layer's xgemm input) and final output.
  if (w == 7 && ln < 4) {
    float z1 = zbuf[ln];
    float z2 = zbuf[4 + ln];
    float za = zbuf[8 + ln];
    float zb = zbuf[12 + ln];
    float f1 = fast_tanh(z1);
    float f2 = fast_tanh(z2);
    float g = 1.f / (1.f + __expf(za * dtv - zb));
    float h = g * f1 + (1.f - g) * f2;
    __hip_atomic_store(&Hout[(size_t)(TT - 1) * DD + bid * 4 + ln], h,
                       __ATOMIC_RELAXED, __HIP_MEMORY_SCOPE_AGENT);
    if (out_last) out_last[bid * 4 + ln] = h;
  }
}

extern "C" void kernel_launch(void* const* d_in, const int* in_sizes, int n_in,
                              void* d_out, int out_size, void* d_ws, size_t ws_size,
                              hipStream_t stream) {
  const float* sp  = (const float*)d_in[0];
  const float* rn  = (const float*)d_in[1];
  const float* dt  = (const float*)d_in[2];
  const float* rw  = (const float*)d_in[3];
  const float* rb  = (const float*)d_in[4];
  const float* Wf1 = (const float*)d_in[5];
  const float* bf1 = (const float*)d_in[6];
  const float* Wf2 = (const float*)d_in[7];
  const float* bf2 = (const float*)d_in[8];
  const float* Wta = (const float*)d_in[9];
  const float* bta = (const float*)d_in[10];
  const float* Wtb = (const float*)d_in[11];
  const float* btb = (const float*)d_in[12];

  float* ws = (float*)d_ws;
  float* A   = ws;                          // [TT, DD]
  float* Bb  = ws + (size_t)TT * DD;        // [TT, DD]
  float* ZX  = ws + (size_t)2 * TT * DD;    // [TT, 4096]
  float* HX  = ws + (size_t)2 * TT * DD + (size_t)TT * 4096;  // [TT,256,16]
  float* out = (float*)d_out;

  dim3 ggrid(32, 16);

#define LAYER(lyr, Xbuf, Hbuf, lastout)                                        \
  do {                                                                         \
    xgemm_kernel<<<ggrid, 256, 0, stream>>>(Xbuf, Wf1, Wf2, Wta, Wtb,          \
        bf1, bf2, bta, btb, ZX, lyr);                                          \
    recur_kernel<<<NBLK, NTHR, 0, stream>>>(ZX, Hbuf, HX, Wf1, Wf2,            \
        Wta, Wtb, dt, lyr, lastout);                                           \
  } while (0)

  // L0: X0 -> A; h-seq -> Bb
  prep_kernel<<<(TT * DD) / 1024, 1024, 0, stream>>>(sp, rn, rw, rb, A);
  LAYER(0, A, Bb, nullptr);
  LAYER(1, Bb, A, nullptr);
  LAYER(2, A, Bb, nullptr);
  LAYER(3, Bb, A, out);
#undef LAYER
}